// Round 1
// 3724.051 us; speedup vs baseline: 1.2953x; 1.2953x over previous
//
#include <hip/hip_runtime.h>
#include <hip/hip_bf16.h>
#include <cmath>
#include <cstdint>

#define LL 8
#define HH 16
#define DD 1024
#define HD 64
#define RR 64
#define FFD 4096
#define VV 50257
#define SS 1024
#define BBS 2
#define QKVN 3072   /* H * (q64 | k64 | v64) interleaved per head */
#define VPAD 50304  /* VV rounded up to 128 so DMA staging never faults */

typedef __attribute__((ext_vector_type(8))) short short8;
typedef __attribute__((ext_vector_type(4))) float f32x4;

__device__ __forceinline__ ushort f2bf(float f) {
  union { float f; uint32_t u; } v; v.f = f;
  uint32_t u = v.u;
  return (ushort)((u + 0x7fffu + ((u >> 16) & 1u)) >> 16);
}

__device__ __forceinline__ float gelu_f(float v) {
  const float c = 0.7978845608028654f;
  float t = tanhf(c * (v + 0.044715f * v * v * v));
  return 0.5f * v * (1.0f + t);
}

// async global->LDS DMA, 16B per lane. LDS dest = wave-uniform base + lane*16.
__device__ __forceinline__ void gl_lds16(const ushort* g, ushort* l) {
  __builtin_amdgcn_global_load_lds(
      (const __attribute__((address_space(1))) unsigned int*)g,
      (__attribute__((address_space(3))) unsigned int*)l, 16, 0, 0);
}

enum { EPI_BIAS = 1, EPI_GELU = 2, EPI_RESID = 4, EPI_F32 = 8, EPI_BF16 = 16 };

// C[M,N] = A[M,K] * B[N,K]^T (+bias/gelu/resid), bf16 inputs, fp32 accum.
// m97 structure: linear LDS + global_load_lds width-16, 2-barrier K-loop.
// M must be a multiple of BM; B rows may run past N (allocations padded),
// garbage columns are masked by the col<N epilogue guard.
template<int BM, int BN, int EPI>
__global__ __launch_bounds__(256) void gemm_nt(
    const ushort* __restrict__ Ab, const ushort* __restrict__ Bbb,
    float* __restrict__ Cb, ushort* __restrict__ Cbfb,
    const float* __restrict__ biasb,
    int M, int N, int K, int lda, int ldb, int ldc,
    long sA0, long sA1, long sB0, long sB1, long sC0, long sC1,
    long sBi0, long sBi1, int zdiv)
{
  constexpr int BK = 32;
  constexpr int WM = BM / 2, WN = BN / 2, ITM = WM / 16, ITN = WN / 16;
  __shared__ __align__(16) ushort As[BM * BK];
  __shared__ __align__(16) ushort Bs[BN * BK];

  const int z = blockIdx.z;
  const int zq = z / zdiv, zr = z % zdiv;
  const ushort* A = Ab + zq * sA0 + zr * sA1;
  const ushort* B = Bbb + zq * sB0 + zr * sB1;

  const int m0 = blockIdx.x * BM;
  const int n0 = blockIdx.y * BN;
  const int tid = threadIdx.x;
  const int lane = tid & 63, wave = tid >> 6;
  const int wm = wave >> 1, wn = wave & 1;
  const int quad = lane >> 4, lm = lane & 15;
  const int srow = lane >> 2;        // row within 16-row DMA chunk
  const int skb = (lane & 3) * 8;    // ushort col offset within row

  f32x4 zero = {0.f, 0.f, 0.f, 0.f};
  f32x4 acc[ITM][ITN];
#pragma unroll
  for (int i = 0; i < ITM; ++i)
#pragma unroll
    for (int j = 0; j < ITN; ++j) acc[i][j] = zero;

  for (int k0 = 0; k0 < K; k0 += BK) {
    __syncthreads();  // previous tile fully consumed before overwrite
    // A tile: BM x 32 bf16, one 1KB chunk (16 rows) per DMA call per wave
#pragma unroll
    for (int it = 0; it < BM / 64; ++it) {
      int c = wave + it * 4;
      gl_lds16(A + (size_t)(m0 + c * 16 + srow) * lda + (k0 + skb), &As[c * 512]);
    }
#pragma unroll
    for (int it = 0; it < BN / 64; ++it) {
      int c = wave + it * 4;
      gl_lds16(B + (size_t)(n0 + c * 16 + srow) * ldb + (k0 + skb), &Bs[c * 512]);
    }
    __syncthreads();  // compiler drains vmcnt before s_barrier -> LDS valid

    short8 af[ITM], bfv[ITN];
#pragma unroll
    for (int i = 0; i < ITM; ++i)
      af[i] = *(const short8*)&As[(wm * WM + i * 16 + lm) * BK + quad * 8];
#pragma unroll
    for (int j = 0; j < ITN; ++j)
      bfv[j] = *(const short8*)&Bs[(wn * WN + j * 16 + lm) * BK + quad * 8];
#pragma unroll
    for (int i = 0; i < ITM; ++i)
#pragma unroll
      for (int j = 0; j < ITN; ++j)
        acc[i][j] = __builtin_amdgcn_mfma_f32_16x16x32_bf16(af[i], bfv[j], acc[i][j], 0, 0, 0);
  }

  float* C = Cb + zq * sC0 + zr * sC1;
  ushort* Cbf = Cbfb + zq * sC0 + zr * sC1;
  const float* bias = biasb + zq * sBi0 + zr * sBi1;

#pragma unroll
  for (int i = 0; i < ITM; ++i) {
    int rbase = m0 + wm * WM + i * 16 + quad * 4;
#pragma unroll
    for (int j = 0; j < ITN; ++j) {
      int col = n0 + wn * WN + j * 16 + lm;
      if (col < N) {
        float bv = (EPI & EPI_BIAS) ? bias[col] : 0.f;
#pragma unroll
        for (int r = 0; r < 4; ++r) {
          float v = acc[i][j][r] + bv;
          if (EPI & EPI_GELU) v = gelu_f(v);
          size_t o = (size_t)(rbase + r) * ldc + col;
          if (EPI & EPI_RESID) v += C[o];
          if (EPI & EPI_F32) C[o] = v;
          if (EPI & EPI_BF16) Cbf[o] = f2bf(v);
        }
      }
    }
  }
}

// fp32 [R_,C_] (row-major) -> bf16 [C_,R_], batched over blockIdx.z
__global__ __launch_bounds__(256) void transpose_cvt(
    const float* __restrict__ in, ushort* __restrict__ out,
    int R_, int C_, long inStride, long outStride)
{
  __shared__ float tile[32][33];
  const long zin = (long)blockIdx.z * inStride;
  const long zout = (long)blockIdx.z * outStride;
  const int c0 = blockIdx.x * 32, r0 = blockIdx.y * 32;
  const int tx = threadIdx.x & 31, ty = threadIdx.x >> 5;
#pragma unroll
  for (int k = 0; k < 4; ++k) {
    int r = r0 + ty + k * 8, c = c0 + tx;
    tile[ty + k * 8][tx] = (r < R_ && c < C_) ? in[zin + (size_t)r * C_ + c] : 0.f;
  }
  __syncthreads();
#pragma unroll
  for (int k = 0; k < 4; ++k) {
    int c = c0 + ty + k * 8, r = r0 + tx;
    if (c < C_ && r < R_) out[zout + (size_t)c * R_ + r] = f2bf(tile[tx][ty + k * 8]);
  }
}

// bf16 [R_,C_] (row stride inLd) -> bf16 [C_,R_]; dims must be x32 multiples
__global__ __launch_bounds__(256) void transpose_bf(
    const ushort* __restrict__ in, ushort* __restrict__ out,
    int R_, int C_, int inLd,
    long sIn0, long sIn1, long sOut0, long sOut1, int zdiv)
{
  __shared__ ushort tile[32][33];
  const int z = blockIdx.z, zq = z / zdiv, zr = z % zdiv;
  const ushort* pin = in + zq * sIn0 + zr * sIn1;
  ushort* pout = out + zq * sOut0 + zr * sOut1;
  const int c0 = blockIdx.x * 32, r0 = blockIdx.y * 32;
  const int tx = threadIdx.x & 31, ty = threadIdx.x >> 5;
#pragma unroll
  for (int k = 0; k < 4; ++k)
    tile[ty + k * 8][tx] = pin[(size_t)(r0 + ty + k * 8) * inLd + c0 + tx];
  __syncthreads();
#pragma unroll
  for (int k = 0; k < 4; ++k)
    pout[(size_t)(c0 + ty + k * 8) * R_ + r0 + tx] = tile[tx][ty + k * 8];
}

// fp32 -> bf16 straight convert (no transpose), 4 elems/thread
__global__ __launch_bounds__(256) void cvt_bf16_kernel(
    const float* __restrict__ in, ushort* __restrict__ out, int n4)
{
  int i = blockIdx.x * 256 + threadIdx.x;
  if (i < n4) {
    float4 v = ((const float4*)in)[i];
    ushort4 o;
    o.x = f2bf(v.x); o.y = f2bf(v.y); o.z = f2bf(v.z); o.w = f2bf(v.w);
    ((ushort4*)out)[i] = o;
  }
}

// build interleaved qkv bias [L][3072]: per head (bq | bk | bvd@Wvu + bvu)
__global__ __launch_bounds__(64) void qkv_bias_kernel(
    const float* __restrict__ bq, const float* __restrict__ bk,
    const float* __restrict__ bvd, const float* __restrict__ Wvu,
    const float* __restrict__ bvu, float* __restrict__ out)
{
  const int z = blockIdx.x;             // l*HH + h
  const int l = z / HH, h = z % HH;
  const int e = threadIdx.x;            // 0..63
  float* o = out + (size_t)l * QKVN + (size_t)h * 192;
  o[e] = bq[(size_t)z * HD + e];
  o[64 + e] = bk[(size_t)z * HD + e];
  float s = bvu[(size_t)z * HD + e];
  const float* wv = Wvu + (size_t)z * RR * HD;
  const float* bv = bvd + (size_t)z * RR;
  for (int r = 0; r < RR; ++r) s += bv[r] * wv[(size_t)r * HD + e];
  o[128 + e] = s;
}

__global__ __launch_bounds__(256) void embed_kernel(
    const int* __restrict__ idx, const float* __restrict__ wte,
    const float* __restrict__ wpe, float* __restrict__ x)
{
  const int rs = blockIdx.x;
  const int s = rs & (SS - 1);
  const int t = idx[rs];
  const float4* a = (const float4*)(wte + (size_t)t * DD);
  const float4* p = (const float4*)(wpe + (size_t)s * DD);
  float4* o = (float4*)(x + (size_t)rs * DD);
  float4 av = a[threadIdx.x], pv = p[threadIdx.x];
  float4 r;
  r.x = av.x + pv.x; r.y = av.y + pv.y; r.z = av.z + pv.z; r.w = av.w + pv.w;
  o[threadIdx.x] = r;
}

__global__ __launch_bounds__(256) void ln_kernel(
    const float* __restrict__ x, const float* __restrict__ g,
    const float* __restrict__ b, ushort* __restrict__ out)
{
  const int row = blockIdx.x;
  const int tid = threadIdx.x;
  const float4* xr = (const float4*)(x + (size_t)row * DD);
  float4 v = xr[tid];
  float s = v.x + v.y + v.z + v.w;
  float sq = v.x * v.x + v.y * v.y + v.z * v.z + v.w * v.w;
#pragma unroll
  for (int o = 32; o > 0; o >>= 1) { s += __shfl_down(s, o); sq += __shfl_down(sq, o); }
  __shared__ float rs_[4], rq_[4];
  if ((tid & 63) == 0) { rs_[tid >> 6] = s; rq_[tid >> 6] = sq; }
  __syncthreads();
  s = rs_[0] + rs_[1] + rs_[2] + rs_[3];
  sq = rq_[0] + rq_[1] + rq_[2] + rq_[3];
  const float mu = s * (1.0f / DD);
  float var = sq * (1.0f / DD) - mu * mu;
  const float rstd = rsqrtf(fmaxf(var, 0.f) + 1e-5f);
  const float4 gv = ((const float4*)g)[tid];
  const float4 bv = ((const float4*)b)[tid];
  ushort4 o4;
  o4.x = f2bf((v.x - mu) * rstd * gv.x + bv.x);
  o4.y = f2bf((v.y - mu) * rstd * gv.y + bv.y);
  o4.z = f2bf((v.z - mu) * rstd * gv.z + bv.z);
  o4.w = f2bf((v.w - mu) * rstd * gv.w + bv.w);
  *(ushort4*)(out + (size_t)row * DD + tid * 4) = o4;
}

// scores row (z,s): mask keeps t >= s (this model attends to self+future).
// Reads fp32 row, writes bf16 P in place (row stride 2*SS ushorts = same bytes).
__global__ __launch_bounds__(256) void softmax_kernel(float* __restrict__ att)
{
  const int zr = blockIdx.x;
  const int s = zr & (SS - 1);
  const int tid = threadIdx.x;
  float* rowf = att + (size_t)zr * SS;
  ushort* rowb = (ushort*)att + (size_t)zr * 2 * SS;
  const float scale = 0.03125f;  // 1/sqrt(1024)
  float vals[4];
  float mx = -1e30f;
#pragma unroll
  for (int k = 0; k < 4; ++k) {
    int t = tid + k * 256;
    float v = rowf[t] * scale;
    vals[k] = (t >= s) ? v : -1e30f;
    mx = fmaxf(mx, vals[k]);
  }
#pragma unroll
  for (int o = 32; o > 0; o >>= 1) mx = fmaxf(mx, __shfl_down(mx, o));
  __shared__ float red[4];
  if ((tid & 63) == 0) red[tid >> 6] = mx;
  __syncthreads();
  mx = fmaxf(fmaxf(red[0], red[1]), fmaxf(red[2], red[3]));
  float e[4]; float l = 0.f;
#pragma unroll
  for (int k = 0; k < 4; ++k) {
    int t = tid + k * 256;
    e[k] = (t >= s) ? __expf(vals[k] - mx) : 0.f;
    l += e[k];
  }
#pragma unroll
  for (int o = 32; o > 0; o >>= 1) l += __shfl_down(l, o);
  __shared__ float red2[4];
  if ((tid & 63) == 0) red2[tid >> 6] = l;
  __syncthreads();
  l = red2[0] + red2[1] + red2[2] + red2[3];
  const float inv = 1.f / l;
#pragma unroll
  for (int k = 0; k < 4; ++k) {
    int t = tid + k * 256;
    rowb[t] = f2bf(e[k] * inv);
  }
}

__global__ __launch_bounds__(256) void loss_kernel(
    const float* __restrict__ logits, const int* __restrict__ labels,
    float* __restrict__ acc)
{
  const int r = blockIdx.x;
  const int tid = threadIdx.x;
  const float* row = logits + (size_t)r * VV;
  float mx = -1e30f;
  for (int t = tid; t < VV; t += 256) mx = fmaxf(mx, row[t]);
#pragma unroll
  for (int o = 32; o > 0; o >>= 1) mx = fmaxf(mx, __shfl_down(mx, o));
  __shared__ float red[4];
  if ((tid & 63) == 0) red[tid >> 6] = mx;
  __syncthreads();
  mx = fmaxf(fmaxf(red[0], red[1]), fmaxf(red[2], red[3]));
  float l = 0.f;
  for (int t = tid; t < VV; t += 256) l += __expf(row[t] - mx);
#pragma unroll
  for (int o = 32; o > 0; o >>= 1) l += __shfl_down(l, o);
  __shared__ float red2[4];
  if ((tid & 63) == 0) red2[tid >> 6] = l;
  __syncthreads();
  if (tid == 0) {
    l = red2[0] + red2[1] + red2[2] + red2[3];
    int lbl = labels[r];
    int lc = lbl < 0 ? 0 : lbl;
    float lp = row[lc] - mx - __logf(l);
    if (lbl != -1) { atomicAdd(acc, -lp); atomicAdd(acc + 1, 1.f); }
  }
}

__global__ void loss_final_kernel(const float* __restrict__ acc, float* __restrict__ o) {
  if (threadIdx.x == 0 && blockIdx.x == 0) o[0] = acc[0] / acc[1];
}

extern "C" void kernel_launch(void* const* d_in, const int* in_sizes, int n_in,
                              void* d_out, int out_size, void* d_ws, size_t ws_size,
                              hipStream_t stream)
{
  const int*   idx    = (const int*)d_in[0];
  const int*   labels = (const int*)d_in[1];
  const float* wte  = (const float*)d_in[2];
  const float* wpe  = (const float*)d_in[3];
  const float* ln1g = (const float*)d_in[4];
  const float* ln1b = (const float*)d_in[5];
  const float* Wq   = (const float*)d_in[6];
  const float* bq   = (const float*)d_in[7];
  const float* Wk   = (const float*)d_in[8];
  const float* bk   = (const float*)d_in[9];
  const float* Wvd  = (const float*)d_in[10];
  const float* bvd  = (const float*)d_in[11];
  const float* Wvu  = (const float*)d_in[12];
  const float* bvu  = (const float*)d_in[13];
  const float* ln2g = (const float*)d_in[14];
  const float* ln2b = (const float*)d_in[15];
  const float* W1   = (const float*)d_in[16];
  const float* b1   = (const float*)d_in[17];
  const float* W2   = (const float*)d_in[18];
  const float* b2   = (const float*)d_in[19];
  const float* lnfg = (const float*)d_in[20];
  const float* lnfb = (const float*)d_in[21];
  const float* Wh   = (const float*)d_in[22];
  const float* bh   = (const float*)d_in[23];
  float* out = (float*)d_out;

  char* ws = (char*)d_ws;
  size_t off = 0;
  auto alloc = [&](size_t bytes) -> char* {
    char* p = ws + off;
    off = (off + bytes + 255) & ~(size_t)255;
    return p;
  };

  // interleaved fused weights [L][3072][D]: per head rows (q64|k64|veff64)
  ushort* Wqkv = (ushort*)alloc((size_t)LL * QKVN * DD * 2);
  float*  qkvb = (float*)alloc((size_t)LL * QKVN * 4);
  ushort* W1T  = (ushort*)alloc((size_t)LL * FFD * DD * 2);
  ushort* W2T  = (ushort*)alloc((size_t)LL * DD * FFD * 2);
  ushort* WhT  = (ushort*)alloc((size_t)VPAD * DD * 2);  // padded: DMA staging reads past VV
  float*  x    = (float*)alloc((size_t)BBS * SS * DD * 4);
  ushort* hbf  = (ushort*)alloc((size_t)BBS * SS * DD * 2);
  ushort* qkv  = (ushort*)alloc((size_t)BBS * SS * QKVN * 2);
  ushort* vT   = (ushort*)alloc((size_t)BBS * HH * HD * SS * 2);
  float*  att  = (float*)alloc((size_t)BBS * HH * SS * SS * 4);
  ushort* mlp1 = (ushort*)alloc((size_t)BBS * SS * FFD * 2);
  float*  lacc = (float*)alloc(256);
  if (off > ws_size) return;  // workspace too small — fail loudly (poison output)

  // setup-only aliases (dead before the layer loop runs)
  ushort* WvuT = (ushort*)att;   // [L*H][HD][RR] bf16, 1 MB
  ushort* Wvdb = mlp1;           // [L*H][D][RR] bf16, exactly 16.8 MB

  float*  dF  = (float*)d_ws;    // dummies for unused epilogue paths
  ushort* dBF = (ushort*)d_ws;

  hipMemsetAsync(lacc, 0, 8, stream);

  dim3 tb(256);

  // ---- one-time (per launch) weight prep ----
  // Wq/Wk transposed straight into the interleaved buffer (z = l*H+h, stride 192*D)
  transpose_cvt<<<dim3(HD / 32, DD / 32, LL * HH), tb, 0, stream>>>(
      Wq, Wqkv, DD, HD, (long)DD * HD, (long)192 * DD);
  transpose_cvt<<<dim3(HD / 32, DD / 32, LL * HH), tb, 0, stream>>>(
      Wk, Wqkv + (size_t)64 * DD, DD, HD, (long)DD * HD, (long)192 * DD);
  // low-rank fold: W_eff^T[e,d] = sum_r Wvu^T[e,r] * Wvd[d,r]
  transpose_cvt<<<dim3(HD / 32, RR / 32, LL * HH), tb, 0, stream>>>(
      Wvu, WvuT, RR, HD, (long)RR * HD, (long)HD * RR);
  cvt_bf16_kernel<<<(LL * HH * DD * RR / 4 + 255) / 256, tb, 0, stream>>>(
      Wvd, Wvdb, LL * HH * DD * RR / 4);
  qkv_bias_kernel<<<LL * HH, 64, 0, stream>>>(bq, bk, bvd, Wvu, bvu, qkvb);
  gemm_nt<64, 128, EPI_BF16><<<dim3(1, DD / 128, LL * HH), tb, 0, stream>>>(
      WvuT, Wvdb, dF, Wqkv + (size_t)128 * DD, dF,
      HD, DD, RR, RR, RR, DD,
      0, (long)HD * RR, 0, (long)DD * RR, 0, (long)192 * DD,
      0, 0, LL * HH);

  transpose_cvt<<<dim3(FFD / 32, DD / 32, LL), tb, 0, stream>>>(
      W1, W1T, DD, FFD, (long)DD * FFD, (long)FFD * DD);
  transpose_cvt<<<dim3(DD / 32, FFD / 32, LL), tb, 0, stream>>>(
      W2, W2T, FFD, DD, (long)FFD * DD, (long)DD * FFD);
  transpose_cvt<<<dim3((VV + 31) / 32, DD / 32, 1), tb, 0, stream>>>(
      Wh, WhT, DD, VV, 0, 0);

  embed_kernel<<<BBS * SS, tb, 0, stream>>>(idx, wte, wpe, x);

  for (int l = 0; l < LL; ++l) {
    ln_kernel<<<BBS * SS, tb, 0, stream>>>(x, ln1g + l * DD, ln1b + l * DD, hbf);

    // fused q|k|v projection: [2048,1024] @ [3072,1024]^T -> [2048,3072] bf16
    gemm_nt<128, 128, EPI_BIAS | EPI_BF16><<<dim3(BBS * SS / 128, QKVN / 128, 1), tb, 0, stream>>>(
        hbf, Wqkv + (size_t)l * QKVN * DD, dF, qkv, qkvb + (size_t)l * QKVN,
        BBS * SS, QKVN, DD, DD, DD, QKVN,
        0, 0, 0, 0, 0, 0, 0, 0, 1);

    // v slice [S,64] (row stride 3072) -> vT [HD,S] bf16 per (b,h)
    transpose_bf<<<dim3(HD / 32, SS / 32, BBS * HH), tb, 0, stream>>>(
        qkv + 128, vT, SS, HD, QKVN,
        (long)SS * QKVN, 192, (long)HH * HD * SS, (long)HD * SS, HH);

    // scores = q @ k^T  (fp32, full S x S)
    gemm_nt<128, 128, EPI_F32><<<dim3(SS / 128, SS / 128, BBS * HH), tb, 0, stream>>>(
        qkv, qkv + 64, att, dBF, dF,
        SS, SS, HD, QKVN, QKVN, SS,
        (long)SS * QKVN, 192, (long)SS * QKVN, 192,
        (long)HH * SS * SS, (long)SS * SS, 0, 0, HH);

    softmax_kernel<<<BBS * HH * SS, tb, 0, stream>>>(att);

    // x += P @ v^T  (per head writes its own D-column slice)
    gemm_nt<128, 64, EPI_RESID | EPI_F32><<<dim3(SS / 128, 1, BBS * HH), tb, 0, stream>>>(
        (const ushort*)att, vT, x, dBF, dF,
        SS, HD, SS, 2 * SS, SS, DD,
        (long)HH * 2 * SS * SS, (long)2 * SS * SS,
        (long)HH * HD * SS, (long)HD * SS,
        (long)SS * DD, (long)HD, 0, 0, HH);

    ln_kernel<<<BBS * SS, tb, 0, stream>>>(x, ln2g + l * DD, ln2b + l * DD, hbf);

    gemm_nt<128, 128, EPI_BIAS | EPI_GELU | EPI_BF16><<<dim3(BBS * SS / 128, FFD / 128, 1), tb, 0, stream>>>(
        hbf, W1T + (size_t)l * FFD * DD, dF, mlp1, b1 + (size_t)l * FFD,
        BBS * SS, FFD, DD, DD, DD, FFD,
        0, 0, 0, 0, 0, 0, 0, 0, 1);

    // 128x64 tile -> 256 blocks (128x128 left half the CUs idle)
    gemm_nt<128, 64, EPI_BIAS | EPI_RESID | EPI_F32><<<dim3(BBS * SS / 128, DD / 64, 1), tb, 0, stream>>>(
        mlp1, W2T + (size_t)l * DD * FFD, x, dBF, b2 + (size_t)l * DD,
        BBS * SS, DD, FFD, FFD, FFD, DD,
        0, 0, 0, 0, 0, 0, 0, 0, 1);
  }

  ln_kernel<<<BBS * SS, tb, 0, stream>>>(x, lnfg, lnfb, hbf);

  gemm_nt<128, 128, EPI_BIAS | EPI_F32><<<dim3(BBS * SS / 128, (VV + 127) / 128, 1), tb, 0, stream>>>(
      hbf, WhT, out, dBF, bh,
      BBS * SS, VV, DD, DD, DD, VV,
      0, 0, 0, 0, 0, 0, 0, 0, 1);

  loss_kernel<<<BBS * SS, tb, 0, stream>>>(out, labels, lacc);
  loss_final_kernel<<<1, 1, 0, stream>>>(lacc, out + (size_t)BBS * SS * VV);
}